// Round 2
// baseline (136486.707 us; speedup 1.0000x reference)
//
#include <hip/hip_runtime.h>
#include <math.h>

typedef unsigned int u32;

// Problem constants
#define T_SEQ   2048
#define BATCH   32
#define DHID    512
#define NWG     256

// Workspace layout (bytes)
#define OFF_HBUF   0              // float[2][32][512] = 131072
#define OFF_ARRIVE 131072         // u32 (256B reserved)
#define OFF_LASTH  131328         // float[32][512]    = 65536

__device__ __forceinline__ void gl2lds16(const void* gsrc, void* ldst) {
  // async global->LDS, 16B per lane; LDS dest = wave-uniform base + lane*16
  __builtin_amdgcn_global_load_lds(
      (const __attribute__((address_space(1))) u32*)gsrc,
      (__attribute__((address_space(3))) u32*)ldst, 16, 0, 0);
}

__device__ __forceinline__ float sigm(float x) { return 1.0f / (1.0f + expf(-x)); }

// Persistent LSTM kernel: 256 WGs x 256 threads, 1 WG/CU.
// WG wg owns hidden units {2wg, 2wg+1} -> 8 gate rows of [W_ih || W_hh] (K=1024).
// Lane mapping (compute): r = tid&7 (gate row), bb = tid>>3 (batch); wave w owns b in [8w,8w+8).
__global__ void __launch_bounds__(256)
lstm_persist(const int* __restrict__ xidx, const int* __restrict__ attn,
             const float* __restrict__ emb,
             const float* __restrict__ Wih, const float* __restrict__ Whh,
             const float* __restrict__ bih, const float* __restrict__ bhh,
             float* __restrict__ hbuf, float* __restrict__ lasth,
             u32* __restrict__ arrive)
{
  // LDS: W slice 32KB + u tiles 16KB + gates 1KB = ~49KB (static, <64KB)
  __shared__ __align__(16) float Wl[8][1024];   // slot sc holds chunk (sc ^ (row&7)) -> conflict-free b128
  __shared__ __align__(16) float ul[2][32][64]; // slot sc holds chunk (sc ^ (b&7))
  __shared__ float gsc[32][8];                  // gates staging / init scratch

  const int tid  = threadIdx.x;
  const int wg   = blockIdx.x;
  const int lane = tid & 63;
  const int wv   = tid >> 6;     // wave 0..3
  const int r    = tid & 7;      // gate row within slice
  const int bb   = tid >> 3;     // batch 0..31
  const int brl  = bb & 7;

  // ---- load W slice, swizzled (one-time) ----
  // global row R for slice row rr: gate = rr>>1, unit = 2wg + (rr&1); R = gate*512 + unit
#pragma unroll 2
  for (int i = 0; i < 8; ++i) {
    int ci = i * 256 + tid;          // chunk id 0..2047 (16B chunks)
    int rr = ci >> 8;                // slice row 0..7
    int cc = ci & 255;               // chunk within 1024-f32 row
    int R  = ((rr >> 1) << 9) + (wg * 2 + (rr & 1));
    const float* src = (cc < 128) ? (Wih + (size_t)R * 512 + cc * 4)
                                  : (Whh + (size_t)R * 512 + (cc - 128) * 4);
    float4 v = *(const float4*)src;
    int slot = cc ^ (rr & 7);
    *(float4*)&Wl[rr][slot * 4] = v;
  }
  float bias;
  {
    int R = ((r >> 1) << 9) + (wg * 2 + (r & 1));
    bias = bih[R] + bhh[R];
  }
  // ---- lengths (scratch in gsc) ----
  {
    int pb = tid >> 3, pc = tid & 7;
    const int4* ap = (const int4*)(attn + pb * 2048 + pc * 256);
    int s = 0;
#pragma unroll 8
    for (int k = 0; k < 64; ++k) { int4 a = ap[k]; s += a.x + a.y + a.z + a.w; }
    gsc[pb][pc] = (float)s;
  }
  __syncthreads();
  int   len_reg = 0;
  float c_reg   = 0.f;
  if (tid < 64) {
    int b2 = tid & 31;
    int s = 0;
#pragma unroll
    for (int k = 0; k < 8; ++k) s += (int)gsc[b2][k];
    len_reg = s - 1;
    if (len_reg < 0) len_reg = 2047;   // all-zero mask -> wrap like hs[-1]
  }
  __syncthreads();

  // per-lane idx prefetch: lane holds x[8w + (lane&7)][t]
  const int idx_b = 8 * wv + (lane & 7);
  int idx_cur = xidx[(size_t)idx_b * 2048];

  for (int t = 0; t < T_SEQ; ++t) {
    int idx_next = (t < T_SEQ - 1) ? xidx[(size_t)idx_b * 2048 + t + 1] : 0;

    float a0 = bias, a1 = 0.f, a2 = 0.f, a3 = 0.f;
    const float* hsrc = hbuf + (((t + 1) & 1) << 14);   // h_{t-1}

    // wave-local stage of 8 rows x 64 f32 (2 rounds x 1KB)
    auto stageE = [&](int jt, int buf) {
#pragma unroll
      for (int q = 0; q < 2; ++q) {
        int rl = 4 * q + (lane >> 4);
        int sc = lane & 15;
        int kc = sc ^ (rl & 7);                 // inverse swizzle on source
        int row = __shfl(idx_cur, rl, 64);
        const float* g = emb + (size_t)row * 512 + jt * 64 + kc * 4;
        gl2lds16(g, (void*)&ul[buf][8 * wv + 4 * q][0]);
      }
    };
    auto stageH = [&](int jt, int buf) {
#pragma unroll
      for (int q = 0; q < 2; ++q) {
        int rl = 4 * q + (lane >> 4);
        int sc = lane & 15;
        int kc = sc ^ (rl & 7);
        int bl = 8 * wv + rl;
        const float* g = hsrc + (size_t)bl * 512 + jt * 64 + kc * 4;
        gl2lds16(g, (void*)&ul[buf][8 * wv + 4 * q][0]);
      }
    };
    auto computeT = [&](int jg, int buf) {      // jg = global tile 0..15
#pragma unroll
      for (int kc = 0; kc < 16; ++kc) {
        float4 uv4 = *(const float4*)&ul[buf][bb][(kc ^ brl) * 4];
        float4 wv4 = *(const float4*)&Wl[r][(((jg << 4) + kc) ^ r) * 4];
        a0 += uv4.x * wv4.x; a1 += uv4.y * wv4.y;
        a2 += uv4.z * wv4.z; a3 += uv4.w * wv4.w;
      }
    };

    // ---- emb phase (independent of h_{t-1}; hides barrier latency) ----
    stageE(0, 0);
#pragma unroll
    for (int jt = 0; jt < 8; ++jt) {
      if (jt < 7) {
        stageE(jt + 1, (jt + 1) & 1);
        asm volatile("s_waitcnt vmcnt(2)" ::: "memory");
      } else {
        asm volatile("s_waitcnt vmcnt(0)" ::: "memory");
      }
      computeT(jt, jt & 1);
    }

    // ---- step barrier: wait for all WGs to have posted h_{t-1} ----
    if (tid == 0) {
      u32 target = (u32)t << 8;                 // 256*t
      while (__hip_atomic_load(arrive, __ATOMIC_RELAXED, __HIP_MEMORY_SCOPE_AGENT) < target)
        __builtin_amdgcn_s_sleep(2);
    }
    __syncthreads();
    __builtin_amdgcn_fence(__ATOMIC_ACQUIRE, "agent");  // invalidate L1/L2 for fresh h

    // ---- h phase ----
    stageH(0, 0);
#pragma unroll
    for (int jt = 0; jt < 8; ++jt) {
      if (jt < 7) {
        stageH(jt + 1, (jt + 1) & 1);
        asm volatile("s_waitcnt vmcnt(2)" ::: "memory");
      } else {
        asm volatile("s_waitcnt vmcnt(0)" ::: "memory");
      }
      computeT(8 + jt, jt & 1);
    }

    // ---- gates -> activations (wave0) -> h_t ----
    gsc[bb][r] = a0 + a1 + a2 + a3;
    __syncthreads();
    if (tid < 64) {
      int u  = tid >> 5;       // unit 0/1
      int b2 = tid & 31;
      float gi = gsc[b2][u];
      float gf = gsc[b2][2 + u];
      float gg = gsc[b2][4 + u];
      float go = gsc[b2][6 + u];
      float iv = sigm(gi), fv = sigm(gf), ov = sigm(go);
      float gv = tanhf(gg);
      c_reg = fv * c_reg + iv * gv;
      float hv = ov * tanhf(c_reg);
      int unit = (wg << 1) + u;
      hbuf[((t & 1) << 14) + (b2 << 9) + unit] = hv;
      if (t == len_reg) lasth[(b2 << 9) + unit] = hv;
      __builtin_amdgcn_fence(__ATOMIC_RELEASE, "agent"); // flush h toward LLC
      if (tid == 0)
        __hip_atomic_fetch_add(arrive, 1u, __ATOMIC_RELAXED, __HIP_MEMORY_SCOPE_AGENT);
    }
    idx_cur = idx_next;
    // no sync needed: next emb staging is wave-local; gsc reuse is ordered by the poll-sync
  }
}

// logits[b][n] = lasth[b] . fc_W[n] + fc_b[n]
__global__ void __launch_bounds__(128)
fc_kernel(const float* __restrict__ lasth, const float* __restrict__ fcW,
          const float* __restrict__ fcb, float* __restrict__ out)
{
  int tid = threadIdx.x;
  int b = tid >> 2, n = tid & 3;
  const float4* h4 = (const float4*)(lasth + (size_t)b * 512);
  const float4* w4 = (const float4*)(fcW + (size_t)n * 512);
  float s0 = 0.f, s1 = 0.f, s2 = 0.f, s3 = 0.f;
#pragma unroll 8
  for (int k = 0; k < 128; ++k) {
    float4 a = h4[k], c = w4[k];
    s0 += a.x * c.x; s1 += a.y * c.y; s2 += a.z * c.z; s3 += a.w * c.w;
  }
  out[b * 4 + n] = fcb[n] + ((s0 + s1) + (s2 + s3));
}

extern "C" void kernel_launch(void* const* d_in, const int* in_sizes, int n_in,
                              void* d_out, int out_size, void* d_ws, size_t ws_size,
                              hipStream_t stream) {
  const int*   x    = (const int*)d_in[0];
  const int*   attn = (const int*)d_in[1];
  const float* emb  = (const float*)d_in[2];
  const float* Wih  = (const float*)d_in[3];
  const float* Whh  = (const float*)d_in[4];
  const float* bih  = (const float*)d_in[5];
  const float* bhh  = (const float*)d_in[6];
  const float* fcW  = (const float*)d_in[7];
  const float* fcb  = (const float*)d_in[8];
  float* out = (float*)d_out;

  char* ws = (char*)d_ws;
  float* hbuf   = (float*)(ws + OFF_HBUF);
  u32*   arrive = (u32*)(ws + OFF_ARRIVE);
  float* lasth  = (float*)(ws + OFF_LASTH);

  // zero h_{-1} (both hbuf halves) and the arrival counter every call (replay-safe)
  (void)hipMemsetAsync(ws, 0, 131072 + 256, stream);

  hipLaunchKernelGGL(lstm_persist, dim3(NWG), dim3(256), 0, stream,
                     x, attn, emb, Wih, Whh, bih, bhh, hbuf, lasth, arrive);
  hipLaunchKernelGGL(fc_kernel, dim3(1), dim3(128), 0, stream,
                     lasth, fcW, fcb, out);
}